// Round 9
// baseline (340.199 us; speedup 1.0000x reference)
//
#include <hip/hip_runtime.h>
#include <stdint.h>

// CausalSelfAttention: B=4 T=2048 C=1024 H=16 D=64
// cast->bf16 | GEMM1 (QKV) | flash-attn (32x32 MFMA, paired q-tiles,
// KVBLK=128, double-buffered K/V + async-stage, 1 barrier/chunk) | GEMM2

#define SEQ 2048
#define NBATCH 4
#define CEMB 1024
#define NHEAD 16
#define DHEAD 64
#define BTROWS (NBATCH * SEQ)  // 8192

typedef __bf16 bf16x8 __attribute__((ext_vector_type(8)));
typedef float f32x4 __attribute__((ext_vector_type(4)));
typedef float f32x16 __attribute__((ext_vector_type(16)));
typedef uint32_t u32x4 __attribute__((ext_vector_type(4)));
typedef unsigned short u16;

__device__ __forceinline__ u16 f2bf(float f) {
  union { float f; uint32_t u; } x; x.f = f;
  uint32_t u = x.u;
  return (u16)((u + 0x7FFFu + ((u >> 16) & 1u)) >> 16);  // RNE
}

__device__ __forceinline__ uint32_t pk2(float a, float b) {
  union { __bf16 h[2]; uint32_t u; } z;
  z.h[0] = (__bf16)a; z.h[1] = (__bf16)b;
  return z.u;
}

__device__ __forceinline__ void gload_lds16(const void* g, void* l) {
  __builtin_amdgcn_global_load_lds(
      (const __attribute__((address_space(1))) uint32_t*)g,
      (__attribute__((address_space(3))) uint32_t*)l, 16, 0, 0);
}

// ---------------- f32 -> bf16 cast ----------------
__global__ __launch_bounds__(256) void cvt_f32_bf16_kernel(
    const float* __restrict__ in, u16* __restrict__ out, int n4) {
  int i = blockIdx.x * blockDim.x + threadIdx.x;
  int stride = gridDim.x * blockDim.x;
  for (; i < n4; i += stride) {
    float4 v = reinterpret_cast<const float4*>(in)[i];
    ushort4 o;
    o.x = f2bf(v.x); o.y = f2bf(v.y); o.z = f2bf(v.z); o.w = f2bf(v.w);
    reinterpret_cast<ushort4*>(out)[i] = o;
  }
}

// ---------------- GEMM: C[M,N] = A[M,K] * Bt[N,K]^T + bias ----------------
template <bool OUT_BF16>
__global__ __launch_bounds__(256) void gemm_bt_kernel(
    const u16* __restrict__ A, const u16* __restrict__ Bt,
    const float* __restrict__ bias, void* __restrict__ Cout,
    int M, int N, int K) {
  __shared__ u16 As[128][64];
  __shared__ u16 Bs[128][64];
  const int tid = threadIdx.x;
  const int lane = tid & 63;
  const int wave = tid >> 6;
  const int wr = wave >> 1, wc = wave & 1;
  const int m0 = blockIdx.y * 128;
  const int n0 = blockIdx.x * 128;
  const int l15 = lane & 15, lhi = lane >> 4;

  f32x4 acc[4][4];
#pragma unroll
  for (int i = 0; i < 4; i++)
#pragma unroll
    for (int j = 0; j < 4; j++) acc[i][j] = (f32x4){0.f, 0.f, 0.f, 0.f};

  const int srow = lane >> 3;
  const int scol = (lane & 7) * 8;

  for (int kt = 0; kt < K; kt += 64) {
#pragma unroll
    for (int i = 0; i < 4; i++) {
      int rr = (wave * 4 + i) * 8 + srow;
      gload_lds16(A + (size_t)(m0 + rr) * K + kt + scol, &As[(wave * 4 + i) * 8][0]);
      gload_lds16(Bt + (size_t)(n0 + rr) * K + kt + scol, &Bs[(wave * 4 + i) * 8][0]);
    }
    __syncthreads();
#pragma unroll
    for (int ks = 0; ks < 2; ks++) {
      bf16x8 af[4], bfr[4];
#pragma unroll
      for (int mi = 0; mi < 4; mi++)
        af[mi] = *(const bf16x8*)&As[wr * 64 + mi * 16 + l15][ks * 32 + lhi * 8];
#pragma unroll
      for (int ni = 0; ni < 4; ni++)
        bfr[ni] = *(const bf16x8*)&Bs[wc * 64 + ni * 16 + l15][ks * 32 + lhi * 8];
#pragma unroll
      for (int mi = 0; mi < 4; mi++)
#pragma unroll
        for (int ni = 0; ni < 4; ni++)
          acc[mi][ni] = __builtin_amdgcn_mfma_f32_16x16x32_bf16(
              af[mi], bfr[ni], acc[mi][ni], 0, 0, 0);
    }
    __syncthreads();
  }

#pragma unroll
  for (int mi = 0; mi < 4; mi++) {
#pragma unroll
    for (int ni = 0; ni < 4; ni++) {
      int n = n0 + wc * 64 + ni * 16 + l15;
      float bv = bias[n];
#pragma unroll
      for (int r = 0; r < 4; r++) {
        int m = m0 + wr * 64 + mi * 16 + lhi * 4 + r;
        float v = acc[mi][ni][r] + bv;
        if constexpr (OUT_BF16)
          ((u16*)Cout)[(size_t)m * N + n] = f2bf(v);
        else
          ((float*)Cout)[(size_t)m * N + n] = v;
      }
    }
  }
}

// ---------------- flash attention --------------------------------------
// QBLK=128 (4 waves x 32 q), KVBLK=128, paired q-tiles {p, 15-p} -> 17
// chunks/block uniformly. Double-buffered K/V LDS; per chunk: issue next
// V-reg loads + K gload_lds FIRST (T14), compute QK^T+softmax, write V^T
// (compiler waits vmcnt on V regs only; K stays in flight), PV, ONE
// __syncthreads (K loads landed under compute -> drain is free).
__global__ __launch_bounds__(256) void attn_kernel(
    const u16* __restrict__ qkv, u16* __restrict__ yatt) {
  __shared__ u16 Ks[2][128][64];   // 2 x 16 KB, XOR-swizzled 16B blocks
  __shared__ u16 Vt[2][64][132];   // 2 x 16.5 KB, V^T [d][key]

  const int tid = threadIdx.x;
  const int lane = tid & 63;
  const int wave = tid >> 6;
  const int p = blockIdx.x;   // 0..7
  const int bh = blockIdx.y;
  const int b = bh >> 4, h = bh & 15;
  const int l31 = lane & 31, hi = lane >> 5;

  const size_t rs = 3 * CEMB;  // 3072
  const u16* qb = qkv + (size_t)b * SEQ * rs + h * DHEAD;
  const u16* kb = qb + CEMB;
  const u16* vb = qb + 2 * CEMB;

  const float SCLL2E = 0.125f * 1.44269504088896f;  // 1/sqrt(D) folded into exp2

  u32x4 tva, tvb2, tvc, tvd;  // V prefetch regs (held across compute)

  for (int pass = 0; pass < 2; ++pass) {
    const int qt = pass ? (15 - p) : p;
    const int q0 = qt * 128;
    const int qabs = q0 + wave * 32 + l31;
    const int nchunk = qt + 1;

    // Q as B-operand: col=q=l31, k = dc*16 + hi*8 + j
    bf16x8 qf[4];
    {
      const u16* qp = qb + (size_t)qabs * rs + hi * 8;
#pragma unroll
      for (int dc = 0; dc < 4; dc++) qf[dc] = *(const bf16x8*)(qp + dc * 16);
    }

    float m_acc = -1e30f, l_acc = 0.f;
    f32x16 o_acc[2];
    o_acc[0] = (f32x16)(0.f);
    o_acc[1] = (f32x16)(0.f);

    // ---- prologue: stage chunk 0 into buffer 0 ----
    {
      const u16* gv0 = vb + (size_t)(0 + lane) * rs + wave * 16;
      const u16* gv1 = vb + (size_t)(64 + lane) * rs + wave * 16;
      tva = *(const u32x4*)gv0; tvb2 = *(const u32x4*)(gv0 + 8);
      tvc = *(const u32x4*)gv1; tvd = *(const u32x4*)(gv1 + 8);
#pragma unroll
      for (int c = 0; c < 4; c++) {
        int row0 = (c * 4 + wave) * 8;
        int row = row0 + (lane >> 3);
        int cb = (lane & 7) ^ (row & 7);
        gload_lds16(kb + (size_t)row * rs + cb * 8, &Ks[0][row0][0]);
      }
      union { u32x4 q; u16 u[8]; } x;
      x.q = tva;
#pragma unroll
      for (int j = 0; j < 8; j++) Vt[0][wave * 16 + j][lane] = x.u[j];
      x.q = tvb2;
#pragma unroll
      for (int j = 0; j < 8; j++) Vt[0][wave * 16 + 8 + j][lane] = x.u[j];
      x.q = tvc;
#pragma unroll
      for (int j = 0; j < 8; j++) Vt[0][wave * 16 + j][64 + lane] = x.u[j];
      x.q = tvd;
#pragma unroll
      for (int j = 0; j < 8; j++) Vt[0][wave * 16 + 8 + j][64 + lane] = x.u[j];
    }
    __syncthreads();

    for (int ci = 0; ci < nchunk; ci++) {
      const int cur = ci & 1;
      const int nxt = cur ^ 1;
      const bool pre = (ci + 1 < nchunk);

      // ---- issue next chunk's loads EARLY (V first = oldest, then K) ----
      if (pre) {
        const int s1 = (ci + 1) * 128;
        const u16* gv0 = vb + (size_t)(s1 + lane) * rs + wave * 16;
        const u16* gv1 = vb + (size_t)(s1 + 64 + lane) * rs + wave * 16;
        tva = *(const u32x4*)gv0; tvb2 = *(const u32x4*)(gv0 + 8);
        tvc = *(const u32x4*)gv1; tvd = *(const u32x4*)(gv1 + 8);
#pragma unroll
        for (int c = 0; c < 4; c++) {
          int row0 = (c * 4 + wave) * 8;
          int row = row0 + (lane >> 3);
          int cb = (lane & 7) ^ (row & 7);
          gload_lds16(kb + (size_t)(s1 + row) * rs + cb * 8, &Ks[nxt][row0][0]);
        }
      }

      // ---- St = K Q^T : sf[kt] C-frag, row=key=kt*32+l31, col=q ----
      f32x16 sf[4];
      __builtin_amdgcn_s_setprio(1);
#pragma unroll
      for (int kt = 0; kt < 4; kt++) {
        f32x16 s = (f32x16)(0.f);
        int key = kt * 32 + l31;
#pragma unroll
        for (int dc = 0; dc < 4; dc++) {
          int cb = (dc * 2 + hi) ^ (key & 7);
          const bf16x8 kf = *(const bf16x8*)((const u16*)&Ks[cur][key][0] + cb * 8);
          s = __builtin_amdgcn_mfma_f32_32x32x16_bf16(kf, qf[dc], s, 0, 0, 0);
        }
        sf[kt] = s;
      }
      __builtin_amdgcn_s_setprio(0);

      // ---- causal mask: only the diagonal chunk ----
      if (ci == nchunk - 1) {
        const int s0 = ci * 128;
#pragma unroll
        for (int kt = 0; kt < 4; kt++)
#pragma unroll
          for (int r = 0; r < 16; r++) {
            int key = s0 + kt * 32 + (r & 3) + 8 * (r >> 2) + 4 * hi;
            if (key > qabs) sf[kt][r] = -3e38f;
          }
      }

      // ---- row max: tree, then 1 cross-half shfl ----
      float t16[16];
#pragma unroll
      for (int i = 0; i < 16; i++)
        t16[i] = fmaxf(fmaxf(sf[0][i], sf[1][i]), fmaxf(sf[2][i], sf[3][i]));
#pragma unroll
      for (int i = 0; i < 8; i++) t16[i] = fmaxf(t16[i], t16[i + 8]);
#pragma unroll
      for (int i = 0; i < 4; i++) t16[i] = fmaxf(t16[i], t16[i + 4]);
      float cmax = fmaxf(fmaxf(t16[0], t16[1]), fmaxf(t16[2], t16[3]));
      cmax = fmaxf(cmax, __shfl_xor(cmax, 32, 64));

      // ---- defer-max (T13) ----
      if (!__all(cmax <= m_acc + 64.0f)) {
        float mnew = fmaxf(m_acc, cmax);
        float scf = __builtin_amdgcn_exp2f((m_acc - mnew) * SCLL2E);
        m_acc = mnew;
        l_acc *= scf;
        float scr[16];
#pragma unroll
        for (int r = 0; r < 16; r++)
          scr[r] = __shfl(scf, (r & 3) + 8 * (r >> 2) + 4 * hi, 64);
#pragma unroll
        for (int r = 0; r < 16; r++) {
          o_acc[0][r] *= scr[r];
          o_acc[1][r] *= scr[r];
        }
      }

      // ---- P = exp2(s*SCLL2E - m*SCLL2E); tree sum ----
      const float c1 = -m_acc * SCLL2E;
#pragma unroll
      for (int kt = 0; kt < 4; kt++)
#pragma unroll
        for (int r = 0; r < 16; r++)
          sf[kt][r] = __builtin_amdgcn_exp2f(fmaf(sf[kt][r], SCLL2E, c1));
#pragma unroll
      for (int i = 0; i < 16; i++)
        t16[i] = (sf[0][i] + sf[1][i]) + (sf[2][i] + sf[3][i]);
#pragma unroll
      for (int i = 0; i < 8; i++) t16[i] = t16[i] + t16[i + 8];
#pragma unroll
      for (int i = 0; i < 4; i++) t16[i] = t16[i] + t16[i + 4];
      float ps = (t16[0] + t16[1]) + (t16[2] + t16[3]);
      ps += __shfl_xor(ps, 32, 64);
      l_acc += ps;

      // ---- P -> A-frag (in-register half-swap) ----
      bf16x8 pa[8];
#pragma unroll
      for (int ks = 0; ks < 8; ks++) {
        const int t = ks >> 1;
        const int ra = (ks & 1) * 8;
        uint32_t a  = pk2(sf[t][ra + 0], sf[t][ra + 1]);
        uint32_t b2 = pk2(sf[t][ra + 2], sf[t][ra + 3]);
        uint32_t cc = pk2(sf[t][ra + 4], sf[t][ra + 5]);
        uint32_t dd = pk2(sf[t][ra + 6], sf[t][ra + 7]);
        uint32_t snd0 = hi ? a : cc;
        uint32_t snd1 = hi ? b2 : dd;
        uint32_t r0 = __shfl_xor(snd0, 32, 64);
        uint32_t r1 = __shfl_xor(snd1, 32, 64);
        union { bf16x8 v; uint32_t w[4]; } u;
        u.w[0] = hi ? r0 : a;
        u.w[1] = hi ? r1 : b2;
        u.w[2] = hi ? cc : r0;
        u.w[3] = hi ? dd : r1;
        pa[ks] = u.v;
      }

      // ---- write next chunk's V^T (compiler inserts vmcnt wait on tv only) ----
      if (pre) {
        union { u32x4 q; u16 u[8]; } x;
        x.q = tva;
#pragma unroll
        for (int j = 0; j < 8; j++) Vt[nxt][wave * 16 + j][lane] = x.u[j];
        x.q = tvb2;
#pragma unroll
        for (int j = 0; j < 8; j++) Vt[nxt][wave * 16 + 8 + j][lane] = x.u[j];
        x.q = tvc;
#pragma unroll
        for (int j = 0; j < 8; j++) Vt[nxt][wave * 16 + j][64 + lane] = x.u[j];
        x.q = tvd;
#pragma unroll
        for (int j = 0; j < 8; j++) Vt[nxt][wave * 16 + 8 + j][64 + lane] = x.u[j];
      }

      // ---- PV: o_acc[dt] += P * V ----
      __builtin_amdgcn_s_setprio(1);
#pragma unroll
      for (int dt = 0; dt < 2; dt++) {
        const u16* vrow = &Vt[cur][dt * 32 + l31][hi * 8];
#pragma unroll
        for (int ks = 0; ks < 8; ks++) {
          union { bf16x8 v; uint2 d[2]; } u;
          u.d[0] = *(const uint2*)(vrow + ks * 16);
          u.d[1] = *(const uint2*)(vrow + ks * 16 + 4);
          o_acc[dt] = __builtin_amdgcn_mfma_f32_32x32x16_bf16(pa[ks], u.v, o_acc[dt], 0, 0, 0);
        }
      }
      __builtin_amdgcn_s_setprio(0);

      __syncthreads();  // single barrier: K loads landed under compute
    }

    // ---- epilogue: O /= l, write bf16 ----
    float rl = 1.0f / l_acc;
#pragma unroll
    for (int r = 0; r < 16; r++) {
      int crow = (r & 3) + 8 * (r >> 2) + 4 * hi;
      float linv = __shfl(rl, crow, 64);
      int t = q0 + wave * 32 + crow;
      u16* yp = yatt + ((size_t)(b * SEQ + t)) * CEMB + h * DHEAD + l31;
      yp[0]  = f2bf(o_acc[0][r] * linv);
      yp[32] = f2bf(o_acc[1][r] * linv);
    }
  }
}

// ---------------- launch ----------------
extern "C" void kernel_launch(void* const* d_in, const int* in_sizes, int n_in,
                              void* d_out, int out_size, void* d_ws, size_t ws_size,
                              hipStream_t stream) {
  const float* x      = (const float*)d_in[0];
  const float* W_attn = (const float*)d_in[1];
  const float* b_attn = (const float*)d_in[2];
  const float* W_proj = (const float*)d_in[3];
  const float* b_proj = (const float*)d_in[4];
  float* out = (float*)d_out;

  u16* Xb   = (u16*)d_ws;                       // 8192*1024
  u16* Wab  = Xb  + (size_t)BTROWS * CEMB;      // 3072*1024
  u16* Wpb  = Wab + (size_t)3 * CEMB * CEMB;    // 1024*1024
  u16* QKV  = Wpb + (size_t)CEMB * CEMB;        // 8192*3072
  u16* Yatt = QKV + (size_t)BTROWS * 3 * CEMB;  // 8192*1024

  cvt_f32_bf16_kernel<<<2048, 256, 0, stream>>>(x, Xb, BTROWS * CEMB / 4);
  cvt_f32_bf16_kernel<<<1024, 256, 0, stream>>>(W_attn, Wab, 3 * CEMB * CEMB / 4);
  cvt_f32_bf16_kernel<<<512, 256, 0, stream>>>(W_proj, Wpb, CEMB * CEMB / 4);

  gemm_bt_kernel<true><<<dim3(3 * CEMB / 128, BTROWS / 128), 256, 0, stream>>>(
      Xb, Wab, b_attn, QKV, BTROWS, 3 * CEMB, CEMB);

  attn_kernel<<<dim3(8, NBATCH * NHEAD), 256, 0, stream>>>(QKV, Yatt);

  gemm_bt_kernel<false><<<dim3(CEMB / 128, BTROWS / 128), 256, 0, stream>>>(
      Yatt, Wpb, b_proj, out, BTROWS, CEMB, CEMB);
}

// Round 11
// 307.470 us; speedup vs baseline: 1.1064x; 1.1064x over previous
//
#include <hip/hip_runtime.h>
#include <stdint.h>

// CausalSelfAttention: B=4 T=2048 C=1024 H=16 D=64
// cast->bf16 | GEMM1 (8-phase 256x256) | flash-attn (round-8) | GEMM2 (8-phase 256x128)

#define SEQ 2048
#define NBATCH 4
#define CEMB 1024
#define NHEAD 16
#define DHEAD 64
#define BTROWS (NBATCH * SEQ)  // 8192

typedef __bf16 bf16x8 __attribute__((ext_vector_type(8)));
typedef float f32x4 __attribute__((ext_vector_type(4)));
typedef float f32x16 __attribute__((ext_vector_type(16)));
typedef uint32_t u32x4 __attribute__((ext_vector_type(4)));
typedef unsigned short u16;

__device__ __forceinline__ u16 f2bf(float f) {
  union { float f; uint32_t u; } x; x.f = f;
  uint32_t u = x.u;
  return (u16)((u + 0x7FFFu + ((u >> 16) & 1u)) >> 16);  // RNE
}

__device__ __forceinline__ uint32_t pk2(float a, float b) {
  union { __bf16 h[2]; uint32_t u; } z;
  z.h[0] = (__bf16)a; z.h[1] = (__bf16)b;
  return z.u;
}

__device__ __forceinline__ void gload_lds16(const void* g, void* l) {
  __builtin_amdgcn_global_load_lds(
      (const __attribute__((address_space(1))) uint32_t*)g,
      (__attribute__((address_space(3))) uint32_t*)l, 16, 0, 0);
}

// ---------------- f32 -> bf16 cast ----------------
__global__ __launch_bounds__(256) void cvt_f32_bf16_kernel(
    const float* __restrict__ in, u16* __restrict__ out, int n4) {
  int i = blockIdx.x * blockDim.x + threadIdx.x;
  int stride = gridDim.x * blockDim.x;
  for (; i < n4; i += stride) {
    float4 v = reinterpret_cast<const float4*>(in)[i];
    ushort4 o;
    o.x = f2bf(v.x); o.y = f2bf(v.y); o.z = f2bf(v.z); o.w = f2bf(v.w);
    reinterpret_cast<ushort4*>(out)[i] = o;
  }
}

// ---------------- 8-phase GEMM: C[M,N] = A[M,K]*Bt[N,K]^T + bias ----------
// BM=256, BK=64, 512 thr = 8 waves (WROWS x WCOLS). Double-buffered LDS with
// 16B-block XOR swizzle (T2): stage pre-swizzles the GLOBAL source, LDS dest
// stays linear (gload_lds requirement); ds_read applies the same XOR.
// Per phase: {ds_read frags; stage; s_barrier; setprio(1); 16 MFMA;
// setprio(0); s_barrier}. Staging front-loaded into phases 0-1 so the
// tile-end __syncthreads (vmcnt drain) is ~free. B-frags held in regs.
template <int BN, int WROWS, bool OUT_BF16>
__global__ __launch_bounds__(512, 2) void gemm8p_kernel(
    const u16* __restrict__ A, const u16* __restrict__ Bt,
    const float* __restrict__ bias, void* __restrict__ Cout,
    int M, int N, int K) {
  constexpr int BM = 256;
  constexpr int WCOLS = 8 / WROWS;
  constexpr int WM = BM / WROWS;   // per-wave rows
  constexpr int WN = BN / WCOLS;   // per-wave cols (64)
  constexpr int MI = WM / 16;
  constexpr int NI = WN / 16;      // 4
  constexpr int PHASES = MI / 2;
  constexpr int ACH = BM / 64;     // A 64-row stage chunks
  constexpr int BCH = BN / 64;     // B 64-row stage chunks

  __shared__ u16 As[2][BM][64];
  __shared__ u16 Bs[2][BN][64];

  const int tid = threadIdx.x;
  const int lane = tid & 63;
  const int wave = tid >> 6;
  const int wr = wave / WCOLS, wc = wave % WCOLS;
  const int l15 = lane & 15, lhi = lane >> 4;

  // XCD-aware bijective swizzle (grids used have nwg % 8 == 0)
  const int nbx = gridDim.x;
  const int nwg = nbx * gridDim.y;
  const int orig = (int)blockIdx.y * nbx + (int)blockIdx.x;
  const int swz = (orig & 7) * (nwg >> 3) + (orig >> 3);
  const int m0 = (swz / nbx) * BM;
  const int n0 = (swz % nbx) * BN;

  const int grow = tid >> 3;  // 0..63 row within 64-row chunk
  const int gcb = tid & 7;    // 16B block within row

  f32x4 acc[MI][NI];
#pragma unroll
  for (int mi = 0; mi < MI; mi++)
#pragma unroll
    for (int ni = 0; ni < NI; ni++) acc[mi][ni] = (f32x4){0.f, 0.f, 0.f, 0.f};

  // ---- prologue: stage tile 0 into buffer 0 ----
#pragma unroll
  for (int c = 0; c < ACH; c++) {
    int row = c * 64 + grow;
    int cb = gcb ^ (row & 7);
    gload_lds16(A + (size_t)(m0 + row) * K + cb * 8, &As[0][row][gcb * 8]);
  }
#pragma unroll
  for (int c = 0; c < BCH; c++) {
    int row = c * 64 + grow;
    int cb = gcb ^ (row & 7);
    gload_lds16(Bt + (size_t)(n0 + row) * K + cb * 8, &Bs[0][row][gcb * 8]);
  }
  __syncthreads();

  const int NT = K / 64;
  for (int t = 0; t < NT; t++) {
    const int cur = t & 1, nxt = cur ^ 1;
    const bool pre = (t + 1 < NT);
    const int kt1 = (t + 1) * 64;
    bf16x8 bfr[NI][2];
#pragma unroll
    for (int p = 0; p < PHASES; p++) {
      // ds-reads for this phase (compiler tracks lgkmcnt deps)
      if (p == 0) {
#pragma unroll
        for (int ni = 0; ni < NI; ni++)
#pragma unroll
          for (int ks = 0; ks < 2; ks++) {
            int row = wc * WN + ni * 16 + l15;
            int b = ks * 4 + lhi;
            bfr[ni][ks] = *(const bf16x8*)&Bs[cur][row][(b ^ (row & 7)) * 8];
          }
      }
      bf16x8 af[2][2];
#pragma unroll
      for (int i = 0; i < 2; i++)
#pragma unroll
        for (int ks = 0; ks < 2; ks++) {
          int row = wr * WM + (p * 2 + i) * 16 + l15;
          int b = ks * 4 + lhi;
          af[i][ks] = *(const bf16x8*)&As[cur][row][(b ^ (row & 7)) * 8];
        }
      // stage next tile, front-loaded: phase 0 -> A, phase 1 -> B
      if (pre && p == 0) {
#pragma unroll
        for (int c = 0; c < ACH; c++) {
          int row = c * 64 + grow;
          int cb = gcb ^ (row & 7);
          gload_lds16(A + (size_t)(m0 + row) * K + kt1 + cb * 8,
                      &As[nxt][row][gcb * 8]);
        }
      }
      if (pre && p == 1) {
#pragma unroll
        for (int c = 0; c < BCH; c++) {
          int row = c * 64 + grow;
          int cb = gcb ^ (row & 7);
          gload_lds16(Bt + (size_t)(n0 + row) * K + kt1 + cb * 8,
                      &Bs[nxt][row][gcb * 8]);
        }
      }
      asm volatile("" ::: "memory");
      __builtin_amdgcn_s_barrier();
      __builtin_amdgcn_s_setprio(1);
#pragma unroll
      for (int ks = 0; ks < 2; ks++)
#pragma unroll
        for (int i = 0; i < 2; i++)
#pragma unroll
          for (int ni = 0; ni < NI; ni++)
            acc[p * 2 + i][ni] = __builtin_amdgcn_mfma_f32_16x16x32_bf16(
                af[i][ks], bfr[ni][ks], acc[p * 2 + i][ni], 0, 0, 0);
      __builtin_amdgcn_s_setprio(0);
      asm volatile("" ::: "memory");
      __builtin_amdgcn_s_barrier();
    }
    __syncthreads();  // tile boundary: drains vmcnt -> staged tile ready; buffer reuse safe
  }

  // ---- epilogue: bias + store ----
  float bv[NI];
#pragma unroll
  for (int ni = 0; ni < NI; ni++) bv[ni] = bias[n0 + wc * WN + ni * 16 + l15];
#pragma unroll
  for (int mi = 0; mi < MI; mi++)
#pragma unroll
    for (int ni = 0; ni < NI; ni++) {
      int n = n0 + wc * WN + ni * 16 + l15;
#pragma unroll
      for (int r = 0; r < 4; r++) {
        int m = m0 + wr * WM + mi * 16 + lhi * 4 + r;
        float v = acc[mi][ni][r] + bv[ni];
        if constexpr (OUT_BF16)
          ((u16*)Cout)[(size_t)m * N + n] = f2bf(v);
        else
          ((float*)Cout)[(size_t)m * N + n] = v;
      }
    }
}

// ---------------- flash attention (round-8 version, measured 134 us) ----
__global__ __launch_bounds__(256) void attn_kernel(
    const u16* __restrict__ qkv, u16* __restrict__ yatt) {
  __shared__ u16 Ks[128][64];   // K chunk, XOR-swizzled 16B blocks (16 KB)
  __shared__ u16 Vt[64][132];   // V^T chunk [d][key] (16.5 KB)

  const int tid = threadIdx.x;
  const int lane = tid & 63;
  const int wave = tid >> 6;
  const int p = blockIdx.x;   // 0..7
  const int bh = blockIdx.y;
  const int b = bh >> 4, h = bh & 15;
  const int l31 = lane & 31, hi = lane >> 5;

  const size_t rs = 3 * CEMB;  // 3072
  const u16* qb = qkv + (size_t)b * SEQ * rs + h * DHEAD;
  const u16* kb = qb + CEMB;
  const u16* vb = qb + 2 * CEMB;

  const float SCLL2E = 0.125f * 1.44269504088896f;

  for (int pass = 0; pass < 2; ++pass) {
    const int qt = pass ? (15 - p) : p;
    const int q0 = qt * 128;
    const int qabs = q0 + wave * 32 + l31;

    bf16x8 qf[4];
    {
      const u16* qp = qb + (size_t)qabs * rs + hi * 8;
#pragma unroll
      for (int dc = 0; dc < 4; dc++) qf[dc] = *(const bf16x8*)(qp + dc * 16);
    }

    float m_acc = -1e30f, l_acc = 0.f;
    f32x16 o_acc[2];
    o_acc[0] = (f32x16)(0.f);
    o_acc[1] = (f32x16)(0.f);

    for (int s0 = 0; s0 <= q0; s0 += 128) {
#pragma unroll
      for (int c = 0; c < 4; c++) {
        int row0 = (c * 4 + wave) * 8;
        int row = row0 + (lane >> 3);
        int cb = (lane & 7) ^ (row & 7);
        gload_lds16(kb + (size_t)(s0 + row) * rs + cb * 8, &Ks[row0][0]);
      }
#pragma unroll
      for (int half = 0; half < 2; ++half) {
        const u16* gv = vb + (size_t)(s0 + half * 64 + lane) * rs + wave * 16;
        union { u32x4 q[2]; u16 u[16]; } tv;
        tv.q[0] = *(const u32x4*)gv;
        tv.q[1] = *(const u32x4*)(gv + 8);
#pragma unroll
        for (int j = 0; j < 16; j++) Vt[wave * 16 + j][half * 64 + lane] = tv.u[j];
      }
      __syncthreads();

      f32x16 sf[4];
      __builtin_amdgcn_s_setprio(1);
#pragma unroll
      for (int kt = 0; kt < 4; kt++) {
        f32x16 s = (f32x16)(0.f);
        int key = kt * 32 + l31;
#pragma unroll
        for (int dc = 0; dc < 4; dc++) {
          int cb = (dc * 2 + hi) ^ (key & 7);
          const bf16x8 kf = *(const bf16x8*)((const u16*)&Ks[key][0] + cb * 8);
          s = __builtin_amdgcn_mfma_f32_32x32x16_bf16(kf, qf[dc], s, 0, 0, 0);
        }
        sf[kt] = s;
      }
      __builtin_amdgcn_s_setprio(0);

      if (s0 == q0) {
#pragma unroll
        for (int kt = 0; kt < 4; kt++)
#pragma unroll
          for (int r = 0; r < 16; r++) {
            int key = s0 + kt * 32 + (r & 3) + 8 * (r >> 2) + 4 * hi;
            if (key > qabs) sf[kt][r] = -3e38f;
          }
      }

      float t16[16];
#pragma unroll
      for (int i = 0; i < 16; i++)
        t16[i] = fmaxf(fmaxf(sf[0][i], sf[1][i]), fmaxf(sf[2][i], sf[3][i]));
#pragma unroll
      for (int i = 0; i < 8; i++) t16[i] = fmaxf(t16[i], t16[i + 8]);
#pragma unroll
      for (int i = 0; i < 4; i++) t16[i] = fmaxf(t16[i], t16[i + 4]);
      float cmax = fmaxf(fmaxf(t16[0], t16[1]), fmaxf(t16[2], t16[3]));
      cmax = fmaxf(cmax, __shfl_xor(cmax, 32, 64));

      if (!__all(cmax <= m_acc + 64.0f)) {
        float mnew = fmaxf(m_acc, cmax);
        float scf = __builtin_amdgcn_exp2f((m_acc - mnew) * SCLL2E);
        m_acc = mnew;
        l_acc *= scf;
        float scr[16];
#pragma unroll
        for (int r = 0; r < 16; r++)
          scr[r] = __shfl(scf, (r & 3) + 8 * (r >> 2) + 4 * hi, 64);
#pragma unroll
        for (int r = 0; r < 16; r++) {
          o_acc[0][r] *= scr[r];
          o_acc[1][r] *= scr[r];
        }
      }

      const float c1 = -m_acc * SCLL2E;
#pragma unroll
      for (int kt = 0; kt < 4; kt++)
#pragma unroll
        for (int r = 0; r < 16; r++)
          sf[kt][r] = __builtin_amdgcn_exp2f(fmaf(sf[kt][r], SCLL2E, c1));
#pragma unroll
      for (int i = 0; i < 16; i++)
        t16[i] = (sf[0][i] + sf[1][i]) + (sf[2][i] + sf[3][i]);
#pragma unroll
      for (int i = 0; i < 8; i++) t16[i] = t16[i] + t16[i + 8];
#pragma unroll
      for (int i = 0; i < 4; i++) t16[i] = t16[i] + t16[i + 4];
      float ps = (t16[0] + t16[1]) + (t16[2] + t16[3]);
      ps += __shfl_xor(ps, 32, 64);
      l_acc += ps;

      bf16x8 pa[8];
#pragma unroll
      for (int ks = 0; ks < 8; ks++) {
        const int t = ks >> 1;
        const int ra = (ks & 1) * 8;
        uint32_t a  = pk2(sf[t][ra + 0], sf[t][ra + 1]);
        uint32_t b2 = pk2(sf[t][ra + 2], sf[t][ra + 3]);
        uint32_t cc = pk2(sf[t][ra + 4], sf[t][ra + 5]);
        uint32_t dd = pk2(sf[t][ra + 6], sf[t][ra + 7]);
        uint32_t snd0 = hi ? a : cc;
        uint32_t snd1 = hi ? b2 : dd;
        uint32_t r0 = __shfl_xor(snd0, 32, 64);
        uint32_t r1 = __shfl_xor(snd1, 32, 64);
        union { bf16x8 v; uint32_t w[4]; } u;
        u.w[0] = hi ? r0 : a;
        u.w[1] = hi ? r1 : b2;
        u.w[2] = hi ? cc : r0;
        u.w[3] = hi ? dd : r1;
        pa[ks] = u.v;
      }

      __builtin_amdgcn_s_setprio(1);
#pragma unroll
      for (int dt = 0; dt < 2; dt++) {
        const u16* vrow = &Vt[dt * 32 + l31][hi * 8];
#pragma unroll
        for (int ks = 0; ks < 8; ks++) {
          union { bf16x8 v; uint2 d[2]; } u;
          u.d[0] = *(const uint2*)(vrow + ks * 16);
          u.d[1] = *(const uint2*)(vrow + ks * 16 + 4);
          o_acc[dt] = __builtin_amdgcn_mfma_f32_32x32x16_bf16(pa[ks], u.v, o_acc[dt], 0, 0, 0);
        }
      }
      __builtin_amdgcn_s_setprio(0);
      __syncthreads();
    }

    float rl = 1.0f / l_acc;
#pragma unroll
    for (int r = 0; r < 16; r++) {
      int crow = (r & 3) + 8 * (r >> 2) + 4 * hi;
      float linv = __shfl(rl, crow, 64);
      int t = q0 + wave * 32 + crow;
      u16* yp = yatt + ((size_t)(b * SEQ + t)) * CEMB + h * DHEAD + l31;
      yp[0]  = f2bf(o_acc[0][r] * linv);
      yp[32] = f2bf(o_acc[1][r] * linv);
    }
  }
}

// ---------------- launch ----------------
extern "C" void kernel_launch(void* const* d_in, const int* in_sizes, int n_in,
                              void* d_out, int out_size, void* d_ws, size_t ws_size,
                              hipStream_t stream) {
  const float* x      = (const float*)d_in[0];
  const float* W_attn = (const float*)d_in[1];
  const float* b_attn = (const float*)d_in[2];
  const float* W_proj = (const float*)d_in[3];
  const float* b_proj = (const float*)d_in[4];
  float* out = (float*)d_out;

  u16* Xb   = (u16*)d_ws;                       // 8192*1024
  u16* Wab  = Xb  + (size_t)BTROWS * CEMB;      // 3072*1024
  u16* Wpb  = Wab + (size_t)3 * CEMB * CEMB;    // 1024*1024
  u16* QKV  = Wpb + (size_t)CEMB * CEMB;        // 8192*3072
  u16* Yatt = QKV + (size_t)BTROWS * 3 * CEMB;  // 8192*1024

  cvt_f32_bf16_kernel<<<2048, 256, 0, stream>>>(x, Xb, BTROWS * CEMB / 4);
  cvt_f32_bf16_kernel<<<1024, 256, 0, stream>>>(W_attn, Wab, 3 * CEMB * CEMB / 4);
  cvt_f32_bf16_kernel<<<512, 256, 0, stream>>>(W_proj, Wpb, CEMB * CEMB / 4);

  // GEMM1: 256x256 tiles -> grid 12 x 32 = 384 blocks (nwg%8==0)
  gemm8p_kernel<256, 2, true><<<dim3(3 * CEMB / 256, BTROWS / 256), 512, 0, stream>>>(
      Xb, Wab, b_attn, QKV, BTROWS, 3 * CEMB, CEMB);

  attn_kernel<<<dim3(8, NBATCH * NHEAD), 256, 0, stream>>>(QKV, Yatt);

  // GEMM2: 256x128 tiles -> grid 8 x 32 = 256 blocks = exactly 1/CU
  gemm8p_kernel<128, 4, false><<<dim3(CEMB / 128, BTROWS / 256), 512, 0, stream>>>(
      Yatt, Wpb, b_proj, out, BTROWS, CEMB, CEMB);
}